// Round 12
// baseline (397.587 us; speedup 1.0000x reference)
//
#include <hip/hip_runtime.h>
#include <hip/hip_bf16.h>

typedef __hip_bfloat16 bf16;
typedef short bf16x8 __attribute__((ext_vector_type(8)));
typedef float f32x4  __attribute__((ext_vector_type(4)));

__device__ __forceinline__ float bf2f(bf16 v){ return __bfloat162float(v); }
__device__ __forceinline__ bf16  f2bf(float f){ return __float2bfloat16(f); }
__device__ __forceinline__ float lrelu(float a){ return a > 0.f ? a : 0.2f*a; }
__device__ __forceinline__ float bfbits(short s){
    union{unsigned u; float f;} cv; cv.u = ((unsigned)(unsigned short)s) << 16; return cv.f;
}
__device__ __forceinline__ short bf16s(float f){ bf16 q = f2bf(f); return *(short*)&q; }

// inline dtype detection: sample 16 even-indexed 16-bit words of `high`.
// bf16 data -> valid normal exponents; f32 low-mantissa halves -> random.
__device__ __forceinline__ int detect_isb(const void* highv){
    const unsigned short* raw = (const unsigned short*)highv;
    int ok = 0;
    #pragma unroll
    for (int i = 0; i < 16; i++){
        int e = (raw[2*i] >> 7) & 0xFF;
        ok += (e >= 90 && e <= 140) ? 1 : 0;
    }
    return ok >= 12;
}

// polymorphic scalar reads (isb wave-uniform)
__device__ __forceinline__ float cvtf(const void* p, int i, int isb){
    return isb ? bf2f(((const bf16*)p)[i]) : ((const float*)p)[i];
}
__device__ __forceinline__ short cvts(const void* p, int i, int isb){
    return isb ? ((const short*)p)[i] : bf16s(((const float*)p)[i]);
}
// load 8 contiguous values as bf16x8 from either bf16 or f32 source
__device__ __forceinline__ bf16x8 load8(const void* base, size_t off, int isb){
    if (isb) return *(const bf16x8*)((const bf16*)base + off);
    const float* f = (const float*)base + off;
    f32x4 v0 = *(const f32x4*)f;
    f32x4 v1 = *(const f32x4*)(f + 4);
    short r[8];
    #pragma unroll
    for (int j = 0; j < 4; j++) r[j]   = bf16s(v0[j]);
    #pragma unroll
    for (int j = 0; j < 4; j++) r[4+j] = bf16s(v1[j]);
    return *(const bf16x8*)r;
}

// ---------------- prep: emb (blocks<nEmb) | pack W1/W2 | degree count ----------------
__global__ __launch_bounds__(256) void k_prep(const void* __restrict__ low,
        const void* __restrict__ Wemb, const void* __restrict__ bemb,
        const void* __restrict__ W1, const void* __restrict__ W2,
        const void* __restrict__ high,
        bf16* __restrict__ emb, bf16* __restrict__ Bp, bf16* __restrict__ Bp2,
        const int* __restrict__ ei, int* __restrict__ counts,
        int N, int E, int nEmb, int nPack, int nCnt){
    __shared__ float wem[2048 + 64];
    __shared__ short lows[1024];
    int t = threadIdx.x;
    int b = blockIdx.x;
    if (b >= nEmb + nPack){
        // degree-count role
        int cb = b - nEmb - nPack;
        int ET = E + N;
        for (int i = cb*256 + t; i < ET; i += nCnt*256){
            int dst = (i < E) ? ei[E + i] : (i - E);
            atomicAdd(&counts[dst], 1);
        }
        return;
    }
    int isb = detect_isb(high);
    if (b >= nEmb){
        // pack role
        int i = (b - nEmb)*256 + t;
        if (i < 16*6*64*8){
            int j = i & 7;
            int lane = (i >> 3) & 63;
            int r = i >> 9;
            int kt = r % 6, nt = r / 6;
            int k = kt*32 + (lane >> 4)*8 + j;
            int n = nt*16 + (lane & 15);
            *(short*)&Bp[i] = cvts(W1, k*256 + n, isb);
        } else {
            int i2 = i - 16*6*64*8;
            if (i2 >= 8*64*8) return;
            int j = i2 & 7;
            int lane = (i2 >> 3) & 63;
            int kt = i2 >> 9;
            int k = kt*32 + (lane >> 4)*8 + j;
            int n = lane & 15;
            *(short*)&Bp2[i2] = (n < 8) ? cvts(W2, k*8 + n, isb) : (short)0;
        }
        return;
    }
    // embedding role: one 32-node tile
    int nb0 = b * 32;
    for (int i = t; i < 2048; i += 256) wem[i] = cvtf(Wemb, i, isb);
    if (t < 64) wem[2048 + t] = cvtf(bemb, t, isb);
    int lim = (N - nb0) * 32; if (lim > 1024) lim = 1024;
    for (int i = t; i < 1024; i += 256)
        lows[i] = (i < lim) ? cvts(low, nb0*32 + i, isb) : (short)0;
    __syncthreads();
    int nl = t >> 3, j8 = (t & 7) * 8;
    float acc[8];
    #pragma unroll
    for (int j = 0; j < 8; j++) acc[j] = wem[2048 + j8 + j];
    for (int k = 0; k < 32; k++){
        float lv = bfbits(lows[nl*32 + k]);
        f32x4 w0 = *(const f32x4*)&wem[k*64 + j8];
        f32x4 w1 = *(const f32x4*)&wem[k*64 + j8 + 4];
        #pragma unroll
        for (int j = 0; j < 4; j++) acc[j]   += lv * w0[j];
        #pragma unroll
        for (int j = 0; j < 4; j++) acc[4+j] += lv * w1[j];
    }
    int n = nb0 + nl;
    if (n < N){
        short ov[8];
        #pragma unroll
        for (int j = 0; j < 8; j++){
            float v = acc[j];
            ov[j] = bf16s(v > 0.f ? v : expm1f(v));
        }
        *(bf16x8*)&emb[(size_t)n*64 + j8] = *(const bf16x8*)ov;
    }
}

// ---------------- single-kernel scan: block b redundantly sums counts[0..b*256) for its offset ----------------
__global__ __launch_bounds__(256) void k_scan(const int* __restrict__ counts,
        int* __restrict__ rowptr, int* __restrict__ cursor, int N, int NB){
    __shared__ int sd[256];
    int b = blockIdx.x, t = threadIdx.x;
    // 1) offset = sum of all previous segments (L2-hot, ~b adds/thread)
    int s = 0;
    for (int i = t; i < b*256; i += 256) s += counts[i];
    sd[t] = s;
    __syncthreads();
    #pragma unroll
    for (int off = 128; off > 0; off >>= 1){
        if (t < off) sd[t] += sd[t + off];
        __syncthreads();
    }
    int offset = sd[0];
    __syncthreads();
    // 2) local exclusive scan of segment b
    int i = b*256 + t;
    int v = (i < N) ? counts[i] : 0;
    sd[t] = v;
    __syncthreads();
    #pragma unroll
    for (int off = 1; off < 256; off <<= 1){
        int a = (t >= off) ? sd[t - off] : 0;
        __syncthreads();
        sd[t] += a;
        __syncthreads();
    }
    if (i < N){
        int r = offset + sd[t] - v;
        rowptr[i] = r;
        cursor[i] = r;
    }
    if (b == NB-1 && t == 255) rowptr[N] = offset + sd[255];
}

__global__ void k_scatter(const int* __restrict__ ei, int E, int N,
        int* __restrict__ cursor, int* __restrict__ srcs){
    int i = blockIdx.x*256 + threadIdx.x;
    int tot = E + N;
    if (i < tot){
        int src, dst;
        if (i < E){ src = ei[i]; dst = ei[E + i]; }
        else      { src = i - E; dst = i - E; }
        int pos = atomicAdd(&cursor[dst], 1);
        srcs[pos] = src;
    }
}

// ---------------- GEMM1 (MFMA, direct-global A/B, fused att scalars) ----------------
__global__ __launch_bounds__(256, 3) void k_gemm1(const void* __restrict__ highv,
        const bf16* __restrict__ emb, const bf16* __restrict__ Bp,
        const void* __restrict__ attS, const void* __restrict__ attD,
        bf16* __restrict__ h1, float* __restrict__ a_s, float* __restrict__ a_d,
        int N){
    const int RS = 260;
    __shared__ float eb[16*260 + 16];
    __shared__ float att[512];
    int t = threadIdx.x;
    int isb = detect_isb(highv);
    att[t] = cvtf(attS, t, isb);
    att[256 + t] = cvtf(attD, t, isb);
    int w = t >> 6, lane = t & 63;
    int m_lo = lane & 15, quad = lane >> 4;
    int m0 = blockIdx.x * 64;
    int mr[4];
    #pragma unroll
    for (int rt = 0; rt < 4; rt++){
        int m = m0 + rt*16 + m_lo;
        mr[rt] = m < N ? m : N-1;
    }
    f32x4 acc[4][4];
    #pragma unroll
    for (int rt = 0; rt < 4; rt++)
        #pragma unroll
        for (int ct = 0; ct < 4; ct++) acc[rt][ct] = (f32x4){0.f,0.f,0.f,0.f};

    #pragma unroll 2
    for (int kt = 0; kt < 6; kt++){
        bf16x8 a[4], b[4];
        if (kt < 4){
            #pragma unroll
            for (int rt = 0; rt < 4; rt++)
                a[rt] = load8(highv, (size_t)mr[rt]*128 + kt*32 + quad*8, isb);
        } else {
            #pragma unroll
            for (int rt = 0; rt < 4; rt++)
                a[rt] = *(const bf16x8*)&emb[(size_t)mr[rt]*64 + (kt-4)*32 + quad*8];
        }
        #pragma unroll
        for (int ct = 0; ct < 4; ct++)
            b[ct] = *(const bf16x8*)&Bp[(size_t)(((w*4 + ct)*6 + kt)*64 + lane)*8];
        #pragma unroll
        for (int rt = 0; rt < 4; rt++)
            #pragma unroll
            for (int ct = 0; ct < 4; ct++)
                acc[rt][ct] = __builtin_amdgcn_mfma_f32_16x16x32_bf16(a[rt], b[ct], acc[rt][ct], 0, 0, 0);
    }

    #pragma unroll 1
    for (int rt = 0; rt < 4; rt++){
        __syncthreads();
        #pragma unroll
        for (int ct = 0; ct < 4; ct++)
            #pragma unroll
            for (int reg = 0; reg < 4; reg++)
                eb[(quad*4 + reg)*RS + w*64 + ct*16 + m_lo] = acc[rt][ct][reg];
        __syncthreads();
        int r = t >> 4, cb = t & 15;
        int c0 = cb * 16;
        int m = m0 + rt*16 + r;
        f32x4 v[4];
        #pragma unroll
        for (int p = 0; p < 4; p++) v[p] = *(const f32x4*)&eb[r*RS + c0 + p*4];
        float ps = 0.f, pd = 0.f;
        #pragma unroll
        for (int p = 0; p < 4; p++)
            #pragma unroll
            for (int j = 0; j < 4; j++){
                ps += v[p][j] * att[c0 + p*4 + j];
                pd += v[p][j] * att[256 + c0 + p*4 + j];
            }
        if (m < N){
            short ov[16];
            #pragma unroll
            for (int p = 0; p < 4; p++)
                #pragma unroll
                for (int j = 0; j < 4; j++) ov[p*4+j] = bf16s(v[p][j]);
            *(bf16x8*)&h1[(size_t)m*256 + c0]     = *(const bf16x8*)&ov[0];
            *(bf16x8*)&h1[(size_t)m*256 + c0 + 8] = *(const bf16x8*)&ov[8];
        }
        ps += __shfl_xor(ps, 1);
        pd += __shfl_xor(pd, 1);
        if (((t & 1) == 0) && m < N){
            int hd = cb >> 1;
            a_s[m*8 + hd] = ps;
            a_d[m*8 + hd] = pd;
        }
    }
}

// ---------------- layer-1: single-sweep unnormalized softmax aggregate + elu + bias ----------------
__global__ __launch_bounds__(256) void k_edge1(const int* __restrict__ rowptr,
        const int* __restrict__ srcs, const float* __restrict__ a_s,
        const float* __restrict__ a_d, const bf16* __restrict__ h1,
        const void* __restrict__ b1, bf16* __restrict__ x2,
        const void* __restrict__ high, int N){
    int t = threadIdx.x;
    int lane = t & 63, wv = t >> 6;
    int n = blockIdx.x*4 + wv;
    if (n >= N) return;
    int beg = rowptr[n];
    int deg = rowptr[n+1] - beg;

    int cl = lane & 31;          // channel group: channels cl*8..cl*8+7
    int hb = cl >> 2;            // head of this group
    int half = lane >> 5;        // edge parity
    float adb = a_d[n*8 + hb];

    float acc[8];
    #pragma unroll
    for (int j = 0; j < 8; j++) acc[j] = 0.f;
    float z = 0.f;

    int e = half;
    for (; e + 6 < deg; e += 8){
        int s0 = srcs[beg + e];
        int s1 = srcs[beg + e + 2];
        int s2 = srcs[beg + e + 4];
        int s3 = srcs[beg + e + 6];
        float w0 = __expf(fminf(lrelu(a_s[s0*8 + hb] + adb), 80.f));
        float w1 = __expf(fminf(lrelu(a_s[s1*8 + hb] + adb), 80.f));
        float w2 = __expf(fminf(lrelu(a_s[s2*8 + hb] + adb), 80.f));
        float w3 = __expf(fminf(lrelu(a_s[s3*8 + hb] + adb), 80.f));
        bf16x8 v0 = *(const bf16x8*)&h1[(size_t)s0*256 + cl*8];
        bf16x8 v1 = *(const bf16x8*)&h1[(size_t)s1*256 + cl*8];
        bf16x8 v2 = *(const bf16x8*)&h1[(size_t)s2*256 + cl*8];
        bf16x8 v3 = *(const bf16x8*)&h1[(size_t)s3*256 + cl*8];
        z += (w0 + w1) + (w2 + w3);
        #pragma unroll
        for (int j = 0; j < 8; j++) acc[j] += w0 * bfbits(v0[j]);
        #pragma unroll
        for (int j = 0; j < 8; j++) acc[j] += w1 * bfbits(v1[j]);
        #pragma unroll
        for (int j = 0; j < 8; j++) acc[j] += w2 * bfbits(v2[j]);
        #pragma unroll
        for (int j = 0; j < 8; j++) acc[j] += w3 * bfbits(v3[j]);
    }
    for (; e < deg; e += 2){
        int s = srcs[beg + e];
        float w = __expf(fminf(lrelu(a_s[s*8 + hb] + adb), 80.f));
        bf16x8 hv = *(const bf16x8*)&h1[(size_t)s*256 + cl*8];
        z += w;
        #pragma unroll
        for (int j = 0; j < 8; j++) acc[j] += w * bfbits(hv[j]);
    }
    #pragma unroll
    for (int j = 0; j < 8; j++) acc[j] += __shfl_xor(acc[j], 32);
    z += __shfl_xor(z, 32);
    float rz = 1.f / (z + 1e-16f);

    if (half == 0){
        int isb = detect_isb(high);
        bf16x8 bv = load8(b1, cl*8, isb);
        short ov[8];
        #pragma unroll
        for (int j = 0; j < 8; j++){
            float v = acc[j] * rz + bfbits(bv[j]);
            ov[j] = bf16s(v > 0.f ? v : expm1f(v));
        }
        *(bf16x8*)&x2[(size_t)n*256 + cl*8] = *(const bf16x8*)ov;
    }
}

// ---------------- GEMM2 (MFMA) + attention scalars layer 2 ----------------
__global__ __launch_bounds__(256) void k_gemm2(const bf16* __restrict__ x2,
        const bf16* __restrict__ Bp2, const void* __restrict__ attS,
        const void* __restrict__ attD, float* __restrict__ h2,
        float* __restrict__ a2s, float* __restrict__ a2d,
        const void* __restrict__ high, int N){
    int t = threadIdx.x;
    int isb = detect_isb(high);
    int w = t >> 6, lane = t & 63;
    int m_lo = lane & 15, quad = lane >> 4;
    int m0 = blockIdx.x*64 + w*16;
    int mr = m0 + m_lo; if (mr >= N) mr = N-1;
    f32x4 acc = (f32x4){0.f,0.f,0.f,0.f};
    #pragma unroll
    for (int kt = 0; kt < 8; kt++){
        bf16x8 a = *(const bf16x8*)&x2[(size_t)mr*256 + kt*32 + quad*8];
        bf16x8 b = *(const bf16x8*)&Bp2[(size_t)(kt*64 + lane)*8];
        acc = __builtin_amdgcn_mfma_f32_16x16x32_bf16(a, b, acc, 0, 0, 0);
    }
    float s2 = (m_lo < 8) ? cvtf(attS, m_lo, isb) : 0.f;
    float d2 = (m_lo < 8) ? cvtf(attD, m_lo, isb) : 0.f;
    #pragma unroll
    for (int reg = 0; reg < 4; reg++){
        int m = m0 + quad*4 + reg;
        float val = acc[reg];
        float ps = val * s2, pd = val * d2;
        ps += __shfl_xor(ps, 1); ps += __shfl_xor(ps, 2);
        ps += __shfl_xor(ps, 4); ps += __shfl_xor(ps, 8);
        pd += __shfl_xor(pd, 1); pd += __shfl_xor(pd, 2);
        pd += __shfl_xor(pd, 4); pd += __shfl_xor(pd, 8);
        if (m < N){
            if (m_lo < 8) h2[(size_t)m*8 + m_lo] = val;
            if (m_lo == 0){ a2s[m] = ps; a2d[m] = pd; }
        }
    }
}

// ---------------- layer-2: single-sweep aggregate + bias + log_softmax ----------------
__global__ __launch_bounds__(256) void k_edge2(const int* __restrict__ rowptr,
        const int* __restrict__ srcs, const float* __restrict__ a2s,
        const float* __restrict__ a2d, const float* __restrict__ h2,
        const void* __restrict__ b2, void* __restrict__ outv,
        const void* __restrict__ high, int N){
    int t = threadIdx.x;
    int lane = t & 63, wv = t >> 6;
    int n = blockIdx.x*4 + wv;
    if (n >= N) return;
    int beg = rowptr[n];
    int deg = rowptr[n+1] - beg;
    float adh = a2d[n];
    int ep = lane >> 3, c = lane & 7;
    float acc = 0.f, z = 0.f;
    for (int e = ep; e < deg; e += 8){
        int s = srcs[beg + e];
        float w = __expf(fminf(lrelu(a2s[s] + adh), 80.f));
        z += w;
        acc += w * h2[(size_t)s*8 + c];
    }
    acc += __shfl_xor(acc, 8);
    acc += __shfl_xor(acc, 16);
    acc += __shfl_xor(acc, 32);
    z += __shfl_xor(z, 8);
    z += __shfl_xor(z, 16);
    z += __shfl_xor(z, 32);
    int isb = detect_isb(high);
    float val = acc / (z + 1e-16f) + cvtf(b2, c, isb);
    float mx = val;
    mx = fmaxf(mx, __shfl_xor(mx, 1));
    mx = fmaxf(mx, __shfl_xor(mx, 2));
    mx = fmaxf(mx, __shfl_xor(mx, 4));
    float se = __expf(val - mx);
    se += __shfl_xor(se, 1); se += __shfl_xor(se, 2); se += __shfl_xor(se, 4);
    float r = val - mx - __logf(se);
    if (lane < 8){
        if (isb) ((bf16*)outv)[(size_t)n*8 + c] = f2bf(r);
        else     ((float*)outv)[(size_t)n*8 + c] = r;
    }
}

extern "C" void kernel_launch(void* const* d_in, const int* in_sizes, int n_in,
                              void* d_out, int out_size, void* d_ws, size_t ws_size,
                              hipStream_t stream) {
    const int* ei = (const int*)d_in[2];
    const int N = in_sizes[0] / 128;
    const int E = in_sizes[2] / 2;
    const int ET = E + N;
    const int NB = (N + 255) / 256;

    char* p = (char*)d_ws;
    auto alloc = [&](size_t bytes) -> void* {
        char* r = p;
        p += (bytes + 255) & ~(size_t)255;
        return (void*)r;
    };
    int*   counts   = (int*)  alloc((size_t)N*4);
    int*   rowptr   = (int*)  alloc((size_t)(N+1)*4);
    int*   cursor   = (int*)  alloc((size_t)N*4);
    int*   srcs     = (int*)  alloc((size_t)ET*4);
    bf16*  Bp       = (bf16*) alloc((size_t)192*256*2);
    bf16*  Bp2      = (bf16*) alloc((size_t)8*64*8*2);
    bf16*  emb      = (bf16*) alloc((size_t)N*64*2);
    bf16*  h1       = (bf16*) alloc((size_t)N*256*2);
    float* a_s      = (float*)alloc((size_t)N*8*4);
    float* a_d      = (float*)alloc((size_t)N*8*4);
    bf16*  x2       = (bf16*) alloc((size_t)N*256*2);
    float* h2       = (float*)alloc((size_t)N*8*4);
    float* a2s      = (float*)alloc((size_t)N*4);
    float* a2d      = (float*)alloc((size_t)N*4);

    hipMemsetAsync(counts, 0, (size_t)N*4, stream);

    {
        int nEmb  = (N + 31)/32;
        int nPack = (16*6*64*8 + 8*64*8 + 255)/256;
        int nCnt  = 1024;
        k_prep<<<nEmb + nPack + nCnt, 256, 0, stream>>>(d_in[1], d_in[3], d_in[4],
                d_in[5], d_in[9], d_in[0], emb, Bp, Bp2, ei, counts, N, E, nEmb, nPack, nCnt);
    }
    k_scan<<<NB, 256, 0, stream>>>(counts, rowptr, cursor, N, NB);
    k_scatter<<<(ET + 255)/256, 256, 0, stream>>>(ei, E, N, cursor, srcs);
    k_gemm1<<<(N + 63)/64, 256, 0, stream>>>(d_in[0], emb, Bp, d_in[6], d_in[7],
                                             h1, a_s, a_d, N);
    k_edge1<<<(N + 3)/4, 256, 0, stream>>>(rowptr, srcs, a_s, a_d, h1, d_in[8], x2, d_in[0], N);
    k_gemm2<<<(N + 63)/64, 256, 0, stream>>>(x2, Bp2, d_in[10], d_in[11], h2, a2s, a2d, d_in[0], N);
    k_edge2<<<(N + 3)/4, 256, 0, stream>>>(rowptr, srcs, a2s, a2d, h2, d_in[12], d_out, d_in[0], N);
}

// Round 13
// 371.433 us; speedup vs baseline: 1.0704x; 1.0704x over previous
//
#include <hip/hip_runtime.h>
#include <hip/hip_bf16.h>

typedef __hip_bfloat16 bf16;
typedef short bf16x8 __attribute__((ext_vector_type(8)));
typedef float f32x4  __attribute__((ext_vector_type(4)));

__device__ __forceinline__ float bf2f(bf16 v){ return __bfloat162float(v); }
__device__ __forceinline__ bf16  f2bf(float f){ return __float2bfloat16(f); }
__device__ __forceinline__ float lrelu(float a){ return a > 0.f ? a : 0.2f*a; }
__device__ __forceinline__ float bfbits(short s){
    union{unsigned u; float f;} cv; cv.u = ((unsigned)(unsigned short)s) << 16; return cv.f;
}
__device__ __forceinline__ short bf16s(float f){ bf16 q = f2bf(f); return *(short*)&q; }
// polymorphic scalar reads (isb wave-uniform)
__device__ __forceinline__ float cvtf(const void* p, int i, int isb){
    return isb ? bf2f(((const bf16*)p)[i]) : ((const float*)p)[i];
}
__device__ __forceinline__ short cvts(const void* p, int i, int isb){
    return isb ? ((const short*)p)[i] : bf16s(((const float*)p)[i]);
}
// load 8 contiguous values as bf16x8 from either bf16 or f32 source
__device__ __forceinline__ bf16x8 load8(const void* base, size_t off, int isb){
    if (isb) return *(const bf16x8*)((const bf16*)base + off);
    const float* f = (const float*)base + off;
    f32x4 v0 = *(const f32x4*)f;
    f32x4 v1 = *(const f32x4*)(f + 4);
    short r[8];
    #pragma unroll
    for (int j = 0; j < 4; j++) r[j]   = bf16s(v0[j]);
    #pragma unroll
    for (int j = 0; j < 4; j++) r[4+j] = bf16s(v1[j]);
    return *(const bf16x8*)r;
}

// ---------------- dtype detection ----------------
__global__ void k_detect(const unsigned short* __restrict__ raw, int* __restrict__ flag){
    int t = threadIdx.x; // 256
    unsigned short w = raw[2*t];
    int e = (w >> 7) & 0xFF;
    int ok = (e >= 90 && e <= 140) ? 1 : 0;
    __shared__ int cnt;
    if (t == 0) cnt = 0;
    __syncthreads();
    atomicAdd(&cnt, ok);
    __syncthreads();
    if (t == 0) *flag = (cnt >= 192) ? 1 : 0;  // 1 = bf16, 0 = f32
}

// ---------------- prep: emb (blocks<nEmb) | pack W1/W2 | degree count ----------------
__global__ __launch_bounds__(256) void k_prep(const void* __restrict__ low,
        const void* __restrict__ Wemb, const void* __restrict__ bemb,
        const void* __restrict__ W1, const void* __restrict__ W2,
        bf16* __restrict__ emb, bf16* __restrict__ Bp, bf16* __restrict__ Bp2,
        const int* __restrict__ ei, int* __restrict__ counts,
        const int* __restrict__ flag, int N, int E, int nEmb, int nPack, int nCnt){
    __shared__ float wem[2048 + 64];
    __shared__ short lows[1024];
    int t = threadIdx.x;
    int b = blockIdx.x;
    int isb = *flag;
    if (b >= nEmb + nPack){
        // degree-count role
        int cb = b - nEmb - nPack;
        int ET = E + N;
        for (int i = cb*256 + t; i < ET; i += nCnt*256){
            int dst = (i < E) ? ei[E + i] : (i - E);
            atomicAdd(&counts[dst], 1);
        }
        return;
    }
    if (b >= nEmb){
        // pack role
        int i = (b - nEmb)*256 + t;
        if (i < 16*6*64*8){
            int j = i & 7;
            int lane = (i >> 3) & 63;
            int r = i >> 9;
            int kt = r % 6, nt = r / 6;
            int k = kt*32 + (lane >> 4)*8 + j;
            int n = nt*16 + (lane & 15);
            *(short*)&Bp[i] = cvts(W1, k*256 + n, isb);
        } else {
            int i2 = i - 16*6*64*8;
            if (i2 >= 8*64*8) return;
            int j = i2 & 7;
            int lane = (i2 >> 3) & 63;
            int kt = i2 >> 9;
            int k = kt*32 + (lane >> 4)*8 + j;
            int n = lane & 15;
            *(short*)&Bp2[i2] = (n < 8) ? cvts(W2, k*8 + n, isb) : (short)0;
        }
        return;
    }
    // embedding role: one 32-node tile
    int nb0 = b * 32;
    for (int i = t; i < 2048; i += 256) wem[i] = cvtf(Wemb, i, isb);
    if (t < 64) wem[2048 + t] = cvtf(bemb, t, isb);
    int lim = (N - nb0) * 32; if (lim > 1024) lim = 1024;
    for (int i = t; i < 1024; i += 256)
        lows[i] = (i < lim) ? cvts(low, nb0*32 + i, isb) : (short)0;
    __syncthreads();
    int nl = t >> 3, j8 = (t & 7) * 8;
    float acc[8];
    #pragma unroll
    for (int j = 0; j < 8; j++) acc[j] = wem[2048 + j8 + j];
    for (int k = 0; k < 32; k++){
        float lv = bfbits(lows[nl*32 + k]);
        f32x4 w0 = *(const f32x4*)&wem[k*64 + j8];
        f32x4 w1 = *(const f32x4*)&wem[k*64 + j8 + 4];
        #pragma unroll
        for (int j = 0; j < 4; j++) acc[j]   += lv * w0[j];
        #pragma unroll
        for (int j = 0; j < 4; j++) acc[4+j] += lv * w1[j];
    }
    int n = nb0 + nl;
    if (n < N){
        short ov[8];
        #pragma unroll
        for (int j = 0; j < 8; j++){
            float v = acc[j];
            ov[j] = bf16s(v > 0.f ? v : expm1f(v));
        }
        *(bf16x8*)&emb[(size_t)n*64 + j8] = *(const bf16x8*)ov;
    }
}

// ---------------- scan phase 1: block-local ----------------
__global__ __launch_bounds__(256) void k_scan_local(const int* __restrict__ counts,
        int* __restrict__ rowptr, int* __restrict__ partials, int N){
    __shared__ int sd[256];
    int t = threadIdx.x;
    int i = blockIdx.x*256 + t;
    int v = (i < N) ? counts[i] : 0;
    sd[t] = v;
    __syncthreads();
    #pragma unroll
    for (int off = 1; off < 256; off <<= 1){
        int a = (t >= off) ? sd[t - off] : 0;
        __syncthreads();
        sd[t] += a;
        __syncthreads();
    }
    if (i < N) rowptr[i] = sd[t] - v;
    if (t == 255) partials[blockIdx.x] = sd[255];
}

// ---------------- scan phase 2 (merged): every block scans partials, applies its offset ----------------
__global__ __launch_bounds__(256) void k_scan_fin(const int* __restrict__ partials,
        int* __restrict__ rowptr, int* __restrict__ cursor, int N, int NB){
    __shared__ int sd[256];
    int b = blockIdx.x, t = threadIdx.x;
    int off = 0, total = 0;
    for (int base = 0; base < NB; base += 256){
        int v = (base + t < NB) ? partials[base + t] : 0;
        __syncthreads();
        sd[t] = v;
        __syncthreads();
        #pragma unroll
        for (int o2 = 1; o2 < 256; o2 <<= 1){
            int a = (t >= o2) ? sd[t - o2] : 0;
            __syncthreads();
            sd[t] += a;
            __syncthreads();
        }
        if (b >= base && b < base + 256){
            int idx = b - base;
            int local = (idx == 0) ? 0 : sd[idx - 1];
            off = total + local;
        }
        total += sd[255];
    }
    int i = b*256 + t;
    if (i < N){
        int r = rowptr[i] + off;
        rowptr[i] = r;
        cursor[i] = r;
    }
    if (b == NB-1 && t == 255) rowptr[N] = total;
}

__global__ void k_scatter(const int* __restrict__ ei, int E, int N,
        int* __restrict__ cursor, int* __restrict__ srcs){
    int i = blockIdx.x*256 + threadIdx.x;
    int tot = E + N;
    if (i < tot){
        int src, dst;
        if (i < E){ src = ei[i]; dst = ei[E + i]; }
        else      { src = i - E; dst = i - E; }
        int pos = atomicAdd(&cursor[dst], 1);
        srcs[pos] = src;
    }
}

// ---------------- GEMM1 (MFMA, direct-global A/B, fused att scalars) ----------------
__global__ __launch_bounds__(256, 3) void k_gemm1(const void* __restrict__ highv,
        const bf16* __restrict__ emb, const bf16* __restrict__ Bp,
        const void* __restrict__ attS, const void* __restrict__ attD,
        bf16* __restrict__ h1, float* __restrict__ a_s, float* __restrict__ a_d,
        const int* __restrict__ flag, int N){
    const int RS = 260;
    __shared__ float eb[16*260 + 16];
    __shared__ float att[512];
    int t = threadIdx.x;
    int isb = *flag;
    att[t] = cvtf(attS, t, isb);
    att[256 + t] = cvtf(attD, t, isb);
    int w = t >> 6, lane = t & 63;
    int m_lo = lane & 15, quad = lane >> 4;
    int m0 = blockIdx.x * 64;
    int mr[4];
    #pragma unroll
    for (int rt = 0; rt < 4; rt++){
        int m = m0 + rt*16 + m_lo;
        mr[rt] = m < N ? m : N-1;
    }
    f32x4 acc[4][4];
    #pragma unroll
    for (int rt = 0; rt < 4; rt++)
        #pragma unroll
        for (int ct = 0; ct < 4; ct++) acc[rt][ct] = (f32x4){0.f,0.f,0.f,0.f};

    #pragma unroll 2
    for (int kt = 0; kt < 6; kt++){
        bf16x8 a[4], b[4];
        if (kt < 4){
            #pragma unroll
            for (int rt = 0; rt < 4; rt++)
                a[rt] = load8(highv, (size_t)mr[rt]*128 + kt*32 + quad*8, isb);
        } else {
            #pragma unroll
            for (int rt = 0; rt < 4; rt++)
                a[rt] = *(const bf16x8*)&emb[(size_t)mr[rt]*64 + (kt-4)*32 + quad*8];
        }
        #pragma unroll
        for (int ct = 0; ct < 4; ct++)
            b[ct] = *(const bf16x8*)&Bp[(size_t)(((w*4 + ct)*6 + kt)*64 + lane)*8];
        #pragma unroll
        for (int rt = 0; rt < 4; rt++)
            #pragma unroll
            for (int ct = 0; ct < 4; ct++)
                acc[rt][ct] = __builtin_amdgcn_mfma_f32_16x16x32_bf16(a[rt], b[ct], acc[rt][ct], 0, 0, 0);
    }

    #pragma unroll 1
    for (int rt = 0; rt < 4; rt++){
        __syncthreads();
        #pragma unroll
        for (int ct = 0; ct < 4; ct++)
            #pragma unroll
            for (int reg = 0; reg < 4; reg++)
                eb[(quad*4 + reg)*RS + w*64 + ct*16 + m_lo] = acc[rt][ct][reg];
        __syncthreads();
        int r = t >> 4, cb = t & 15;
        int c0 = cb * 16;
        int m = m0 + rt*16 + r;
        f32x4 v[4];
        #pragma unroll
        for (int p = 0; p < 4; p++) v[p] = *(const f32x4*)&eb[r*RS + c0 + p*4];
        float ps = 0.f, pd = 0.f;
        #pragma unroll
        for (int p = 0; p < 4; p++)
            #pragma unroll
            for (int j = 0; j < 4; j++){
                ps += v[p][j] * att[c0 + p*4 + j];
                pd += v[p][j] * att[256 + c0 + p*4 + j];
            }
        if (m < N){
            short ov[16];
            #pragma unroll
            for (int p = 0; p < 4; p++)
                #pragma unroll
                for (int j = 0; j < 4; j++) ov[p*4+j] = bf16s(v[p][j]);
            *(bf16x8*)&h1[(size_t)m*256 + c0]     = *(const bf16x8*)&ov[0];
            *(bf16x8*)&h1[(size_t)m*256 + c0 + 8] = *(const bf16x8*)&ov[8];
        }
        ps += __shfl_xor(ps, 1);
        pd += __shfl_xor(pd, 1);
        if (((t & 1) == 0) && m < N){
            int hd = cb >> 1;
            a_s[m*8 + hd] = ps;
            a_d[m*8 + hd] = pd;
        }
    }
}

// ---------------- layer-1: single-sweep unnormalized softmax aggregate + elu + bias ----------------
__global__ __launch_bounds__(256) void k_edge1(const int* __restrict__ rowptr,
        const int* __restrict__ srcs, const float* __restrict__ a_s,
        const float* __restrict__ a_d, const bf16* __restrict__ h1,
        const void* __restrict__ b1, bf16* __restrict__ x2,
        const int* __restrict__ flag, int N){
    int t = threadIdx.x;
    int lane = t & 63, wv = t >> 6;
    int n = blockIdx.x*4 + wv;
    if (n >= N) return;
    int beg = rowptr[n];
    int deg = rowptr[n+1] - beg;

    int cl = lane & 31;          // channel group: channels cl*8..cl*8+7
    int hb = cl >> 2;            // head of this group
    int half = lane >> 5;        // edge parity
    float adb = a_d[n*8 + hb];

    float acc[8];
    #pragma unroll
    for (int j = 0; j < 8; j++) acc[j] = 0.f;
    float z = 0.f;

    int e = half;
    for (; e + 6 < deg; e += 8){
        int s0 = srcs[beg + e];
        int s1 = srcs[beg + e + 2];
        int s2 = srcs[beg + e + 4];
        int s3 = srcs[beg + e + 6];
        float w0 = __expf(fminf(lrelu(a_s[s0*8 + hb] + adb), 80.f));
        float w1 = __expf(fminf(lrelu(a_s[s1*8 + hb] + adb), 80.f));
        float w2 = __expf(fminf(lrelu(a_s[s2*8 + hb] + adb), 80.f));
        float w3 = __expf(fminf(lrelu(a_s[s3*8 + hb] + adb), 80.f));
        bf16x8 v0 = *(const bf16x8*)&h1[(size_t)s0*256 + cl*8];
        bf16x8 v1 = *(const bf16x8*)&h1[(size_t)s1*256 + cl*8];
        bf16x8 v2 = *(const bf16x8*)&h1[(size_t)s2*256 + cl*8];
        bf16x8 v3 = *(const bf16x8*)&h1[(size_t)s3*256 + cl*8];
        z += (w0 + w1) + (w2 + w3);
        #pragma unroll
        for (int j = 0; j < 8; j++) acc[j] += w0 * bfbits(v0[j]);
        #pragma unroll
        for (int j = 0; j < 8; j++) acc[j] += w1 * bfbits(v1[j]);
        #pragma unroll
        for (int j = 0; j < 8; j++) acc[j] += w2 * bfbits(v2[j]);
        #pragma unroll
        for (int j = 0; j < 8; j++) acc[j] += w3 * bfbits(v3[j]);
    }
    for (; e < deg; e += 2){
        int s = srcs[beg + e];
        float w = __expf(fminf(lrelu(a_s[s*8 + hb] + adb), 80.f));
        bf16x8 hv = *(const bf16x8*)&h1[(size_t)s*256 + cl*8];
        z += w;
        #pragma unroll
        for (int j = 0; j < 8; j++) acc[j] += w * bfbits(hv[j]);
    }
    #pragma unroll
    for (int j = 0; j < 8; j++) acc[j] += __shfl_xor(acc[j], 32);
    z += __shfl_xor(z, 32);
    float rz = 1.f / (z + 1e-16f);

    if (half == 0){
        int isb = *flag;
        bf16x8 bv = load8(b1, cl*8, isb);
        short ov[8];
        #pragma unroll
        for (int j = 0; j < 8; j++){
            float v = acc[j] * rz + bfbits(bv[j]);
            ov[j] = bf16s(v > 0.f ? v : expm1f(v));
        }
        *(bf16x8*)&x2[(size_t)n*256 + cl*8] = *(const bf16x8*)ov;
    }
}

// ---------------- GEMM2 (MFMA) + attention scalars layer 2 ----------------
__global__ __launch_bounds__(256) void k_gemm2(const bf16* __restrict__ x2,
        const bf16* __restrict__ Bp2, const void* __restrict__ attS,
        const void* __restrict__ attD, float* __restrict__ h2,
        float* __restrict__ a2s, float* __restrict__ a2d,
        const int* __restrict__ flag, int N){
    int t = threadIdx.x;
    int isb = *flag;
    int w = t >> 6, lane = t & 63;
    int m_lo = lane & 15, quad = lane >> 4;
    int m0 = blockIdx.x*64 + w*16;
    int mr = m0 + m_lo; if (mr >= N) mr = N-1;
    f32x4 acc = (f32x4){0.f,0.f,0.f,0.f};
    #pragma unroll
    for (int kt = 0; kt < 8; kt++){
        bf16x8 a = *(const bf16x8*)&x2[(size_t)mr*256 + kt*32 + quad*8];
        bf16x8 b = *(const bf16x8*)&Bp2[(size_t)(kt*64 + lane)*8];
        acc = __builtin_amdgcn_mfma_f32_16x16x32_bf16(a, b, acc, 0, 0, 0);
    }
    float s2 = (m_lo < 8) ? cvtf(attS, m_lo, isb) : 0.f;
    float d2 = (m_lo < 8) ? cvtf(attD, m_lo, isb) : 0.f;
    #pragma unroll
    for (int reg = 0; reg < 4; reg++){
        int m = m0 + quad*4 + reg;
        float val = acc[reg];
        float ps = val * s2, pd = val * d2;
        ps += __shfl_xor(ps, 1); ps += __shfl_xor(ps, 2);
        ps += __shfl_xor(ps, 4); ps += __shfl_xor(ps, 8);
        pd += __shfl_xor(pd, 1); pd += __shfl_xor(pd, 2);
        pd += __shfl_xor(pd, 4); pd += __shfl_xor(pd, 8);
        if (m < N){
            if (m_lo < 8) h2[(size_t)m*8 + m_lo] = val;
            if (m_lo == 0){ a2s[m] = ps; a2d[m] = pd; }
        }
    }
}

// ---------------- layer-2: single-sweep aggregate + bias + log_softmax ----------------
__global__ __launch_bounds__(256) void k_edge2(const int* __restrict__ rowptr,
        const int* __restrict__ srcs, const float* __restrict__ a2s,
        const float* __restrict__ a2d, const float* __restrict__ h2,
        const void* __restrict__ b2, void* __restrict__ outv,
        const int* __restrict__ flag, int N){
    int t = threadIdx.x;
    int lane = t & 63, wv = t >> 6;
    int n = blockIdx.x*4 + wv;
    if (n >= N) return;
    int beg = rowptr[n];
    int deg = rowptr[n+1] - beg;
    float adh = a2d[n];
    int ep = lane >> 3, c = lane & 7;
    float acc = 0.f, z = 0.f;
    for (int e = ep; e < deg; e += 8){
        int s = srcs[beg + e];
        float w = __expf(fminf(lrelu(a2s[s] + adh), 80.f));
        z += w;
        acc += w * h2[(size_t)s*8 + c];
    }
    acc += __shfl_xor(acc, 8);
    acc += __shfl_xor(acc, 16);
    acc += __shfl_xor(acc, 32);
    z += __shfl_xor(z, 8);
    z += __shfl_xor(z, 16);
    z += __shfl_xor(z, 32);
    int isb = *flag;
    float val = acc / (z + 1e-16f) + cvtf(b2, c, isb);
    float mx = val;
    mx = fmaxf(mx, __shfl_xor(mx, 1));
    mx = fmaxf(mx, __shfl_xor(mx, 2));
    mx = fmaxf(mx, __shfl_xor(mx, 4));
    float se = __expf(val - mx);
    se += __shfl_xor(se, 1); se += __shfl_xor(se, 2); se += __shfl_xor(se, 4);
    float r = val - mx - __logf(se);
    if (lane < 8){
        if (isb) ((bf16*)outv)[(size_t)n*8 + c] = f2bf(r);
        else     ((float*)outv)[(size_t)n*8 + c] = r;
    }
}

extern "C" void kernel_launch(void* const* d_in, const int* in_sizes, int n_in,
                              void* d_out, int out_size, void* d_ws, size_t ws_size,
                              hipStream_t stream) {
    const int* ei = (const int*)d_in[2];
    const int N = in_sizes[0] / 128;
    const int E = in_sizes[2] / 2;
    const int ET = E + N;
    const int NB = (N + 255) / 256;

    char* p = (char*)d_ws;
    auto alloc = [&](size_t bytes) -> void* {
        char* r = p;
        p += (bytes + 255) & ~(size_t)255;
        return (void*)r;
    };
    int*   flag     = (int*)  alloc(256);
    int*   counts   = (int*)  alloc((size_t)N*4);
    int*   rowptr   = (int*)  alloc((size_t)(N+1)*4);
    int*   cursor   = (int*)  alloc((size_t)N*4);
    int*   srcs     = (int*)  alloc((size_t)ET*4);
    int*   partials = (int*)  alloc((size_t)NB*4);
    bf16*  Bp       = (bf16*) alloc((size_t)192*256*2);
    bf16*  Bp2      = (bf16*) alloc((size_t)8*64*8*2);
    bf16*  emb      = (bf16*) alloc((size_t)N*64*2);
    bf16*  h1       = (bf16*) alloc((size_t)N*256*2);
    float* a_s      = (float*)alloc((size_t)N*8*4);
    float* a_d      = (float*)alloc((size_t)N*8*4);
    bf16*  x2       = (bf16*) alloc((size_t)N*256*2);
    float* h2       = (float*)alloc((size_t)N*8*4);
    float* a2s      = (float*)alloc((size_t)N*4);
    float* a2d      = (float*)alloc((size_t)N*4);

    k_detect<<<1, 256, 0, stream>>>((const unsigned short*)d_in[0], flag);
    hipMemsetAsync(counts, 0, (size_t)N*4, stream);

    {
        int nEmb  = (N + 31)/32;
        int nPack = (16*6*64*8 + 8*64*8 + 255)/256;
        int nCnt  = 1024;
        k_prep<<<nEmb + nPack + nCnt, 256, 0, stream>>>(d_in[1], d_in[3], d_in[4],
                d_in[5], d_in[9], emb, Bp, Bp2, ei, counts, flag, N, E, nEmb, nPack, nCnt);
    }
    k_scan_local<<<NB, 256, 0, stream>>>(counts, rowptr, partials, N);
    k_scan_fin  <<<NB, 256, 0, stream>>>(partials, rowptr, cursor, N, NB);
    k_scatter<<<(ET + 255)/256, 256, 0, stream>>>(ei, E, N, cursor, srcs);
    k_gemm1<<<(N + 63)/64, 256, 0, stream>>>(d_in[0], emb, Bp, d_in[6], d_in[7],
                                             h1, a_s, a_d, flag, N);
    k_edge1<<<(N + 3)/4, 256, 0, stream>>>(rowptr, srcs, a_s, a_d, h1, d_in[8], x2, flag, N);
    k_gemm2<<<(N + 63)/64, 256, 0, stream>>>(x2, Bp2, d_in[10], d_in[11], h2, a2s, a2d, flag, N);
    k_edge2<<<(N + 3)/4, 256, 0, stream>>>(rowptr, srcs, a2s, a2d, h2, d_in[12], d_out, flag, N);
}

// Round 14
// 358.976 us; speedup vs baseline: 1.1076x; 1.0347x over previous
//
#include <hip/hip_runtime.h>
#include <hip/hip_bf16.h>

typedef __hip_bfloat16 bf16;
typedef short bf16x8 __attribute__((ext_vector_type(8)));
typedef float f32x4  __attribute__((ext_vector_type(4)));

__device__ __forceinline__ float bf2f(bf16 v){ return __bfloat162float(v); }
__device__ __forceinline__ bf16  f2bf(float f){ return __float2bfloat16(f); }
__device__ __forceinline__ float lrelu(float a){ return a > 0.f ? a : 0.2f*a; }
__device__ __forceinline__ float bfbits(short s){
    union{unsigned u; float f;} cv; cv.u = ((unsigned)(unsigned short)s) << 16; return cv.f;
}
__device__ __forceinline__ short bf16s(float f){ bf16 q = f2bf(f); return *(short*)&q; }
// polymorphic scalar reads (isb wave-uniform)
__device__ __forceinline__ float cvtf(const void* p, int i, int isb){
    return isb ? bf2f(((const bf16*)p)[i]) : ((const float*)p)[i];
}
__device__ __forceinline__ short cvts(const void* p, int i, int isb){
    return isb ? ((const short*)p)[i] : bf16s(((const float*)p)[i]);
}
// load 8 contiguous values as bf16x8 from either bf16 or f32 source
__device__ __forceinline__ bf16x8 load8(const void* base, size_t off, int isb){
    if (isb) return *(const bf16x8*)((const bf16*)base + off);
    const float* f = (const float*)base + off;
    f32x4 v0 = *(const f32x4*)f;
    f32x4 v1 = *(const f32x4*)(f + 4);
    short r[8];
    #pragma unroll
    for (int j = 0; j < 4; j++) r[j]   = bf16s(v0[j]);
    #pragma unroll
    for (int j = 0; j < 4; j++) r[4+j] = bf16s(v1[j]);
    return *(const bf16x8*)r;
}

// ---------------- init: zero counts (all blocks) + dtype detect (block 0) ----------------
__global__ void k_init(const unsigned short* __restrict__ raw, int* __restrict__ flag,
        int* __restrict__ counts, int N){
    int t = threadIdx.x;
    int i = blockIdx.x*256 + t;
    if (i < N) counts[i] = 0;
    if (blockIdx.x == 0){
        unsigned short w = raw[2*t];
        int e = (w >> 7) & 0xFF;
        int ok = (e >= 90 && e <= 140) ? 1 : 0;
        __shared__ int cnt;
        if (t == 0) cnt = 0;
        __syncthreads();
        atomicAdd(&cnt, ok);
        __syncthreads();
        if (t == 0) *flag = (cnt >= 192) ? 1 : 0;  // 1 = bf16, 0 = f32
    }
}

// ---------------- prep: emb (blocks<nEmb) | pack W1/W2 | degree count ----------------
__global__ __launch_bounds__(256) void k_prep(const void* __restrict__ low,
        const void* __restrict__ Wemb, const void* __restrict__ bemb,
        const void* __restrict__ W1, const void* __restrict__ W2,
        bf16* __restrict__ emb, bf16* __restrict__ Bp, bf16* __restrict__ Bp2,
        const int* __restrict__ ei, int* __restrict__ counts,
        const int* __restrict__ flag, int N, int E, int nEmb, int nPack, int nCnt){
    __shared__ float wem[2048 + 64];
    __shared__ short lows[1024];
    int t = threadIdx.x;
    int b = blockIdx.x;
    int isb = *flag;
    if (b >= nEmb + nPack){
        // degree-count role
        int cb = b - nEmb - nPack;
        int ET = E + N;
        for (int i = cb*256 + t; i < ET; i += nCnt*256){
            int dst = (i < E) ? ei[E + i] : (i - E);
            atomicAdd(&counts[dst], 1);
        }
        return;
    }
    if (b >= nEmb){
        // pack role
        int i = (b - nEmb)*256 + t;
        if (i < 16*6*64*8){
            int j = i & 7;
            int lane = (i >> 3) & 63;
            int r = i >> 9;
            int kt = r % 6, nt = r / 6;
            int k = kt*32 + (lane >> 4)*8 + j;
            int n = nt*16 + (lane & 15);
            *(short*)&Bp[i] = cvts(W1, k*256 + n, isb);
        } else {
            int i2 = i - 16*6*64*8;
            if (i2 >= 8*64*8) return;
            int j = i2 & 7;
            int lane = (i2 >> 3) & 63;
            int kt = i2 >> 9;
            int k = kt*32 + (lane >> 4)*8 + j;
            int n = lane & 15;
            *(short*)&Bp2[i2] = (n < 8) ? cvts(W2, k*8 + n, isb) : (short)0;
        }
        return;
    }
    // embedding role: one 32-node tile
    int nb0 = b * 32;
    for (int i = t; i < 2048; i += 256) wem[i] = cvtf(Wemb, i, isb);
    if (t < 64) wem[2048 + t] = cvtf(bemb, t, isb);
    int lim = (N - nb0) * 32; if (lim > 1024) lim = 1024;
    for (int i = t; i < 1024; i += 256)
        lows[i] = (i < lim) ? cvts(low, nb0*32 + i, isb) : (short)0;
    __syncthreads();
    int nl = t >> 3, j8 = (t & 7) * 8;
    float acc[8];
    #pragma unroll
    for (int j = 0; j < 8; j++) acc[j] = wem[2048 + j8 + j];
    for (int k = 0; k < 32; k++){
        float lv = bfbits(lows[nl*32 + k]);
        f32x4 w0 = *(const f32x4*)&wem[k*64 + j8];
        f32x4 w1 = *(const f32x4*)&wem[k*64 + j8 + 4];
        #pragma unroll
        for (int j = 0; j < 4; j++) acc[j]   += lv * w0[j];
        #pragma unroll
        for (int j = 0; j < 4; j++) acc[4+j] += lv * w1[j];
    }
    int n = nb0 + nl;
    if (n < N){
        short ov[8];
        #pragma unroll
        for (int j = 0; j < 8; j++){
            float v = acc[j];
            ov[j] = bf16s(v > 0.f ? v : expm1f(v));
        }
        *(bf16x8*)&emb[(size_t)n*64 + j8] = *(const bf16x8*)ov;
    }
}

// ---------------- scan phase 1: block-local ----------------
__global__ __launch_bounds__(256) void k_scan_local(const int* __restrict__ counts,
        int* __restrict__ rowptr, int* __restrict__ partials, int N){
    __shared__ int sd[256];
    int t = threadIdx.x;
    int i = blockIdx.x*256 + t;
    int v = (i < N) ? counts[i] : 0;
    sd[t] = v;
    __syncthreads();
    #pragma unroll
    for (int off = 1; off < 256; off <<= 1){
        int a = (t >= off) ? sd[t - off] : 0;
        __syncthreads();
        sd[t] += a;
        __syncthreads();
    }
    if (i < N) rowptr[i] = sd[t] - v;
    if (t == 255) partials[blockIdx.x] = sd[255];
}

// ---------------- scan phase 2: every block scans partials, applies its offset ----------------
__global__ __launch_bounds__(256) void k_scan_fin(const int* __restrict__ partials,
        int* __restrict__ rowptr, int* __restrict__ cursor, int N, int NB){
    __shared__ int sd[256];
    int b = blockIdx.x, t = threadIdx.x;
    int off = 0, total = 0;
    for (int base = 0; base < NB; base += 256){
        int v = (base + t < NB) ? partials[base + t] : 0;
        __syncthreads();
        sd[t] = v;
        __syncthreads();
        #pragma unroll
        for (int o2 = 1; o2 < 256; o2 <<= 1){
            int a = (t >= o2) ? sd[t - o2] : 0;
            __syncthreads();
            sd[t] += a;
            __syncthreads();
        }
        if (b >= base && b < base + 256){
            int idx = b - base;
            int local = (idx == 0) ? 0 : sd[idx - 1];
            off = total + local;
        }
        total += sd[255];
    }
    int i = b*256 + t;
    if (i < N){
        int r = rowptr[i] + off;
        rowptr[i] = r;
        cursor[i] = r;
    }
    if (b == NB-1 && t == 255) rowptr[N] = total;
}

// ---------------- merged: GEMM1 (blocks < nG) | scatter (blocks >= nG) ----------------
// Both roles' dependencies are satisfied after scan_fin; they stress disjoint
// resources (MFMA/streaming vs atomics/scattered-writes) and overlap on the CUs.
__global__ __launch_bounds__(256, 3) void k_sg(
        const int* __restrict__ ei, int* __restrict__ cursor, int* __restrict__ srcs,
        const void* __restrict__ highv, const bf16* __restrict__ emb,
        const bf16* __restrict__ Bp, const void* __restrict__ attS,
        const void* __restrict__ attD, bf16* __restrict__ h1,
        float* __restrict__ a_s, float* __restrict__ a_d,
        const int* __restrict__ flag, int N, int E, int nG){
    const int RS = 260;
    __shared__ float eb[16*260 + 16];
    __shared__ float att[512];
    int t = threadIdx.x;
    if ((int)blockIdx.x >= nG){
        // ---- scatter role ----
        int i = (blockIdx.x - nG)*256 + t;
        int tot = E + N;
        if (i < tot){
            int src, dst;
            if (i < E){ src = ei[i]; dst = ei[E + i]; }
            else      { src = i - E; dst = i - E; }
            int pos = atomicAdd(&cursor[dst], 1);
            srcs[pos] = src;
        }
        return;
    }
    // ---- GEMM1 role ----
    int isb = *flag;
    att[t] = cvtf(attS, t, isb);
    att[256 + t] = cvtf(attD, t, isb);
    int w = t >> 6, lane = t & 63;
    int m_lo = lane & 15, quad = lane >> 4;
    int m0 = blockIdx.x * 64;
    int mr[4];
    #pragma unroll
    for (int rt = 0; rt < 4; rt++){
        int m = m0 + rt*16 + m_lo;
        mr[rt] = m < N ? m : N-1;
    }
    f32x4 acc[4][4];
    #pragma unroll
    for (int rt = 0; rt < 4; rt++)
        #pragma unroll
        for (int ct = 0; ct < 4; ct++) acc[rt][ct] = (f32x4){0.f,0.f,0.f,0.f};

    #pragma unroll 2
    for (int kt = 0; kt < 6; kt++){
        bf16x8 a[4], b[4];
        if (kt < 4){
            #pragma unroll
            for (int rt = 0; rt < 4; rt++)
                a[rt] = load8(highv, (size_t)mr[rt]*128 + kt*32 + quad*8, isb);
        } else {
            #pragma unroll
            for (int rt = 0; rt < 4; rt++)
                a[rt] = *(const bf16x8*)&emb[(size_t)mr[rt]*64 + (kt-4)*32 + quad*8];
        }
        #pragma unroll
        for (int ct = 0; ct < 4; ct++)
            b[ct] = *(const bf16x8*)&Bp[(size_t)(((w*4 + ct)*6 + kt)*64 + lane)*8];
        #pragma unroll
        for (int rt = 0; rt < 4; rt++)
            #pragma unroll
            for (int ct = 0; ct < 4; ct++)
                acc[rt][ct] = __builtin_amdgcn_mfma_f32_16x16x32_bf16(a[rt], b[ct], acc[rt][ct], 0, 0, 0);
    }

    #pragma unroll 1
    for (int rt = 0; rt < 4; rt++){
        __syncthreads();
        #pragma unroll
        for (int ct = 0; ct < 4; ct++)
            #pragma unroll
            for (int reg = 0; reg < 4; reg++)
                eb[(quad*4 + reg)*RS + w*64 + ct*16 + m_lo] = acc[rt][ct][reg];
        __syncthreads();
        int r = t >> 4, cb = t & 15;
        int c0 = cb * 16;
        int m = m0 + rt*16 + r;
        f32x4 v[4];
        #pragma unroll
        for (int p = 0; p < 4; p++) v[p] = *(const f32x4*)&eb[r*RS + c0 + p*4];
        float ps = 0.f, pd = 0.f;
        #pragma unroll
        for (int p = 0; p < 4; p++)
            #pragma unroll
            for (int j = 0; j < 4; j++){
                ps += v[p][j] * att[c0 + p*4 + j];
                pd += v[p][j] * att[256 + c0 + p*4 + j];
            }
        if (m < N){
            short ov[16];
            #pragma unroll
            for (int p = 0; p < 4; p++)
                #pragma unroll
                for (int j = 0; j < 4; j++) ov[p*4+j] = bf16s(v[p][j]);
            *(bf16x8*)&h1[(size_t)m*256 + c0]     = *(const bf16x8*)&ov[0];
            *(bf16x8*)&h1[(size_t)m*256 + c0 + 8] = *(const bf16x8*)&ov[8];
        }
        ps += __shfl_xor(ps, 1);
        pd += __shfl_xor(pd, 1);
        if (((t & 1) == 0) && m < N){
            int hd = cb >> 1;
            a_s[m*8 + hd] = ps;
            a_d[m*8 + hd] = pd;
        }
    }
}

// ---------------- layer-1: single-sweep unnormalized softmax aggregate + elu + bias ----------------
__global__ __launch_bounds__(256) void k_edge1(const int* __restrict__ rowptr,
        const int* __restrict__ srcs, const float* __restrict__ a_s,
        const float* __restrict__ a_d, const bf16* __restrict__ h1,
        const void* __restrict__ b1, bf16* __restrict__ x2,
        const int* __restrict__ flag, int N){
    int t = threadIdx.x;
    int lane = t & 63, wv = t >> 6;
    int n = blockIdx.x*4 + wv;
    if (n >= N) return;
    int beg = rowptr[n];
    int deg = rowptr[n+1] - beg;

    int cl = lane & 31;          // channel group: channels cl*8..cl*8+7
    int hb = cl >> 2;            // head of this group
    int half = lane >> 5;        // edge parity
    float adb = a_d[n*8 + hb];

    float acc[8];
    #pragma unroll
    for (int j = 0; j < 8; j++) acc[j] = 0.f;
    float z = 0.f;

    int e = half;
    for (; e + 6 < deg; e += 8){
        int s0 = srcs[beg + e];
        int s1 = srcs[beg + e + 2];
        int s2 = srcs[beg + e + 4];
        int s3 = srcs[beg + e + 6];
        float w0 = __expf(fminf(lrelu(a_s[s0*8 + hb] + adb), 80.f));
        float w1 = __expf(fminf(lrelu(a_s[s1*8 + hb] + adb), 80.f));
        float w2 = __expf(fminf(lrelu(a_s[s2*8 + hb] + adb), 80.f));
        float w3 = __expf(fminf(lrelu(a_s[s3*8 + hb] + adb), 80.f));
        bf16x8 v0 = *(const bf16x8*)&h1[(size_t)s0*256 + cl*8];
        bf16x8 v1 = *(const bf16x8*)&h1[(size_t)s1*256 + cl*8];
        bf16x8 v2 = *(const bf16x8*)&h1[(size_t)s2*256 + cl*8];
        bf16x8 v3 = *(const bf16x8*)&h1[(size_t)s3*256 + cl*8];
        z += (w0 + w1) + (w2 + w3);
        #pragma unroll
        for (int j = 0; j < 8; j++) acc[j] += w0 * bfbits(v0[j]);
        #pragma unroll
        for (int j = 0; j < 8; j++) acc[j] += w1 * bfbits(v1[j]);
        #pragma unroll
        for (int j = 0; j < 8; j++) acc[j] += w2 * bfbits(v2[j]);
        #pragma unroll
        for (int j = 0; j < 8; j++) acc[j] += w3 * bfbits(v3[j]);
    }
    for (; e < deg; e += 2){
        int s = srcs[beg + e];
        float w = __expf(fminf(lrelu(a_s[s*8 + hb] + adb), 80.f));
        bf16x8 hv = *(const bf16x8*)&h1[(size_t)s*256 + cl*8];
        z += w;
        #pragma unroll
        for (int j = 0; j < 8; j++) acc[j] += w * bfbits(hv[j]);
    }
    #pragma unroll
    for (int j = 0; j < 8; j++) acc[j] += __shfl_xor(acc[j], 32);
    z += __shfl_xor(z, 32);
    float rz = 1.f / (z + 1e-16f);

    if (half == 0){
        int isb = *flag;
        bf16x8 bv = load8(b1, cl*8, isb);
        short ov[8];
        #pragma unroll
        for (int j = 0; j < 8; j++){
            float v = acc[j] * rz + bfbits(bv[j]);
            ov[j] = bf16s(v > 0.f ? v : expm1f(v));
        }
        *(bf16x8*)&x2[(size_t)n*256 + cl*8] = *(const bf16x8*)ov;
    }
}

// ---------------- GEMM2 (MFMA) + attention scalars layer 2 ----------------
__global__ __launch_bounds__(256) void k_gemm2(const bf16* __restrict__ x2,
        const bf16* __restrict__ Bp2, const void* __restrict__ attS,
        const void* __restrict__ attD, float* __restrict__ h2,
        float* __restrict__ a2s, float* __restrict__ a2d,
        const int* __restrict__ flag, int N){
    int t = threadIdx.x;
    int isb = *flag;
    int w = t >> 6, lane = t & 63;
    int m_lo = lane & 15, quad = lane >> 4;
    int m0 = blockIdx.x*64 + w*16;
    int mr = m0 + m_lo; if (mr >= N) mr = N-1;
    f32x4 acc = (f32x4){0.f,0.f,0.f,0.f};
    #pragma unroll
    for (int kt = 0; kt < 8; kt++){
        bf16x8 a = *(const bf16x8*)&x2[(size_t)mr*256 + kt*32 + quad*8];
        bf16x8 b = *(const bf16x8*)&Bp2[(size_t)(kt*64 + lane)*8];
        acc = __builtin_amdgcn_mfma_f32_16x16x32_bf16(a, b, acc, 0, 0, 0);
    }
    float s2 = (m_lo < 8) ? cvtf(attS, m_lo, isb) : 0.f;
    float d2 = (m_lo < 8) ? cvtf(attD, m_lo, isb) : 0.f;
    #pragma unroll
    for (int reg = 0; reg < 4; reg++){
        int m = m0 + quad*4 + reg;
        float val = acc[reg];
        float ps = val * s2, pd = val * d2;
        ps += __shfl_xor(ps, 1); ps += __shfl_xor(ps, 2);
        ps += __shfl_xor(ps, 4); ps += __shfl_xor(ps, 8);
        pd += __shfl_xor(pd, 1); pd += __shfl_xor(pd, 2);
        pd += __shfl_xor(pd, 4); pd += __shfl_xor(pd, 8);
        if (m < N){
            if (m_lo < 8) h2[(size_t)m*8 + m_lo] = val;
            if (m_lo == 0){ a2s[m] = ps; a2d[m] = pd; }
        }
    }
}

// ---------------- layer-2: single-sweep aggregate + bias + log_softmax ----------------
__global__ __launch_bounds__(256) void k_edge2(const int* __restrict__ rowptr,
        const int* __restrict__ srcs, const float* __restrict__ a2s,
        const float* __restrict__ a2d, const float* __restrict__ h2,
        const void* __restrict__ b2, void* __restrict__ outv,
        const int* __restrict__ flag, int N){
    int t = threadIdx.x;
    int lane = t & 63, wv = t >> 6;
    int n = blockIdx.x*4 + wv;
    if (n >= N) return;
    int beg = rowptr[n];
    int deg = rowptr[n+1] - beg;
    float adh = a2d[n];
    int ep = lane >> 3, c = lane & 7;
    float acc = 0.f, z = 0.f;
    for (int e = ep; e < deg; e += 8){
        int s = srcs[beg + e];
        float w = __expf(fminf(lrelu(a2s[s] + adh), 80.f));
        z += w;
        acc += w * h2[(size_t)s*8 + c];
    }
    acc += __shfl_xor(acc, 8);
    acc += __shfl_xor(acc, 16);
    acc += __shfl_xor(acc, 32);
    z += __shfl_xor(z, 8);
    z += __shfl_xor(z, 16);
    z += __shfl_xor(z, 32);
    int isb = *flag;
    float val = acc / (z + 1e-16f) + cvtf(b2, c, isb);
    float mx = val;
    mx = fmaxf(mx, __shfl_xor(mx, 1));
    mx = fmaxf(mx, __shfl_xor(mx, 2));
    mx = fmaxf(mx, __shfl_xor(mx, 4));
    float se = __expf(val - mx);
    se += __shfl_xor(se, 1); se += __shfl_xor(se, 2); se += __shfl_xor(se, 4);
    float r = val - mx - __logf(se);
    if (lane < 8){
        if (isb) ((bf16*)outv)[(size_t)n*8 + c] = f2bf(r);
        else     ((float*)outv)[(size_t)n*8 + c] = r;
    }
}

extern "C" void kernel_launch(void* const* d_in, const int* in_sizes, int n_in,
                              void* d_out, int out_size, void* d_ws, size_t ws_size,
                              hipStream_t stream) {
    const int* ei = (const int*)d_in[2];
    const int N = in_sizes[0] / 128;
    const int E = in_sizes[2] / 2;
    const int ET = E + N;
    const int NB = (N + 255) / 256;

    char* p = (char*)d_ws;
    auto alloc = [&](size_t bytes) -> void* {
        char* r = p;
        p += (bytes + 255) & ~(size_t)255;
        return (void*)r;
    };
    int*   flag     = (int*)  alloc(256);
    int*   counts   = (int*)  alloc((size_t)N*4);
    int*   rowptr   = (int*)  alloc((size_t)(N+1)*4);
    int*   cursor   = (int*)  alloc((size_t)N*4);
    int*   srcs     = (int*)  alloc((size_t)ET*4);
    int*   partials = (int*)  alloc((size_t)NB*4);
    bf16*  Bp       = (bf16*) alloc((size_t)192*256*2);
    bf16*  Bp2      = (bf16*) alloc((size_t)8*64*8*2);
    bf16*  emb      = (bf16*) alloc((size_t)N*64*2);
    bf16*  h1       = (bf16*) alloc((size_t)N*256*2);
    float* a_s      = (float*)alloc((size_t)N*8*4);
    float* a_d      = (float*)alloc((size_t)N*8*4);
    bf16*  x2       = (bf16*) alloc((size_t)N*256*2);
    float* h2       = (float*)alloc((size_t)N*8*4);
    float* a2s      = (float*)alloc((size_t)N*4);
    float* a2d      = (float*)alloc((size_t)N*4);

    k_init<<<NB, 256, 0, stream>>>((const unsigned short*)d_in[0], flag, counts, N);

    {
        int nEmb  = (N + 31)/32;
        int nPack = (16*6*64*8 + 8*64*8 + 255)/256;
        int nCnt  = 1024;
        k_prep<<<nEmb + nPack + nCnt, 256, 0, stream>>>(d_in[1], d_in[3], d_in[4],
                d_in[5], d_in[9], emb, Bp, Bp2, ei, counts, flag, N, E, nEmb, nPack, nCnt);
    }
    k_scan_local<<<NB, 256, 0, stream>>>(counts, rowptr, partials, N);
    k_scan_fin  <<<NB, 256, 0, stream>>>(partials, rowptr, cursor, N, NB);
    {
        int nG = (N + 63)/64;
        int nScat = (ET + 255)/256;
        k_sg<<<nG + nScat, 256, 0, stream>>>(ei, cursor, srcs,
                d_in[0], emb, Bp, d_in[6], d_in[7], h1, a_s, a_d, flag, N, E, nG);
    }
    k_edge1<<<(N + 3)/4, 256, 0, stream>>>(rowptr, srcs, a_s, a_d, h1, d_in[8], x2, flag, N);
    k_gemm2<<<(N + 63)/64, 256, 0, stream>>>(x2, Bp2, d_in[10], d_in[11], h2, a2s, a2d, flag, N);
    k_edge2<<<(N + 3)/4, 256, 0, stream>>>(rowptr, srcs, a2s, a2d, h2, d_in[12], d_out, flag, N);
}

// Round 15
// 355.766 us; speedup vs baseline: 1.1176x; 1.0090x over previous
//
#include <hip/hip_runtime.h>
#include <hip/hip_bf16.h>

typedef __hip_bfloat16 bf16;
typedef short bf16x8 __attribute__((ext_vector_type(8)));
typedef float f32x4  __attribute__((ext_vector_type(4)));

__device__ __forceinline__ float bf2f(bf16 v){ return __bfloat162float(v); }
__device__ __forceinline__ bf16  f2bf(float f){ return __float2bfloat16(f); }
__device__ __forceinline__ float lrelu(float a){ return a > 0.f ? a : 0.2f*a; }
__device__ __forceinline__ float bfbits(short s){
    union{unsigned u; float f;} cv; cv.u = ((unsigned)(unsigned short)s) << 16; return cv.f;
}
__device__ __forceinline__ short bf16s(float f){ bf16 q = f2bf(f); return *(short*)&q; }
// polymorphic scalar reads (isb wave-uniform)
__device__ __forceinline__ float cvtf(const void* p, int i, int isb){
    return isb ? bf2f(((const bf16*)p)[i]) : ((const float*)p)[i];
}
__device__ __forceinline__ short cvts(const void* p, int i, int isb){
    return isb ? ((const short*)p)[i] : bf16s(((const float*)p)[i]);
}
// load 8 contiguous values as bf16x8 from either bf16 or f32 source
__device__ __forceinline__ bf16x8 load8(const void* base, size_t off, int isb){
    if (isb) return *(const bf16x8*)((const bf16*)base + off);
    const float* f = (const float*)base + off;
    f32x4 v0 = *(const f32x4*)f;
    f32x4 v1 = *(const f32x4*)(f + 4);
    short r[8];
    #pragma unroll
    for (int j = 0; j < 4; j++) r[j]   = bf16s(v0[j]);
    #pragma unroll
    for (int j = 0; j < 4; j++) r[4+j] = bf16s(v1[j]);
    return *(const bf16x8*)r;
}

// ---------------- init: counts=1 (self-loop pre-counted) + dtype detect (block 0) ----------------
__global__ void k_init(const unsigned short* __restrict__ raw, int* __restrict__ flag,
        int* __restrict__ counts, int N){
    int t = threadIdx.x;
    int i = blockIdx.x*256 + t;
    if (i < N) counts[i] = 1;
    if (blockIdx.x == 0){
        unsigned short w = raw[2*t];
        int e = (w >> 7) & 0xFF;
        int ok = (e >= 90 && e <= 140) ? 1 : 0;
        __shared__ int cnt;
        if (t == 0) cnt = 0;
        __syncthreads();
        atomicAdd(&cnt, ok);
        __syncthreads();
        if (t == 0) *flag = (cnt >= 192) ? 1 : 0;  // 1 = bf16, 0 = f32
    }
}

// ---------------- prep: emb (blocks<nEmb) | pack W1/W2 | degree count (real edges only) ----------------
__global__ __launch_bounds__(256) void k_prep(const void* __restrict__ low,
        const void* __restrict__ Wemb, const void* __restrict__ bemb,
        const void* __restrict__ W1, const void* __restrict__ W2,
        bf16* __restrict__ emb, bf16* __restrict__ Bp, bf16* __restrict__ Bp2,
        const int* __restrict__ ei, int* __restrict__ counts,
        const int* __restrict__ flag, int N, int E, int nEmb, int nPack, int nCnt){
    __shared__ float wem[2048 + 64];
    __shared__ short lows[1024];
    int t = threadIdx.x;
    int b = blockIdx.x;
    int isb = *flag;
    if (b >= nEmb + nPack){
        // degree-count role: only the E real edges (self-loops pre-counted in k_init)
        int cb = b - nEmb - nPack;
        for (int i = cb*256 + t; i < E; i += nCnt*256){
            atomicAdd(&counts[ei[E + i]], 1);
        }
        return;
    }
    if (b >= nEmb){
        // pack role
        int i = (b - nEmb)*256 + t;
        if (i < 16*6*64*8){
            int j = i & 7;
            int lane = (i >> 3) & 63;
            int r = i >> 9;
            int kt = r % 6, nt = r / 6;
            int k = kt*32 + (lane >> 4)*8 + j;
            int n = nt*16 + (lane & 15);
            *(short*)&Bp[i] = cvts(W1, k*256 + n, isb);
        } else {
            int i2 = i - 16*6*64*8;
            if (i2 >= 8*64*8) return;
            int j = i2 & 7;
            int lane = (i2 >> 3) & 63;
            int kt = i2 >> 9;
            int k = kt*32 + (lane >> 4)*8 + j;
            int n = lane & 15;
            *(short*)&Bp2[i2] = (n < 8) ? cvts(W2, k*8 + n, isb) : (short)0;
        }
        return;
    }
    // embedding role: one 32-node tile
    int nb0 = b * 32;
    for (int i = t; i < 2048; i += 256) wem[i] = cvtf(Wemb, i, isb);
    if (t < 64) wem[2048 + t] = cvtf(bemb, t, isb);
    int lim = (N - nb0) * 32; if (lim > 1024) lim = 1024;
    for (int i = t; i < 1024; i += 256)
        lows[i] = (i < lim) ? cvts(low, nb0*32 + i, isb) : (short)0;
    __syncthreads();
    int nl = t >> 3, j8 = (t & 7) * 8;
    float acc[8];
    #pragma unroll
    for (int j = 0; j < 8; j++) acc[j] = wem[2048 + j8 + j];
    for (int k = 0; k < 32; k++){
        float lv = bfbits(lows[nl*32 + k]);
        f32x4 w0 = *(const f32x4*)&wem[k*64 + j8];
        f32x4 w1 = *(const f32x4*)&wem[k*64 + j8 + 4];
        #pragma unroll
        for (int j = 0; j < 4; j++) acc[j]   += lv * w0[j];
        #pragma unroll
        for (int j = 0; j < 4; j++) acc[4+j] += lv * w1[j];
    }
    int n = nb0 + nl;
    if (n < N){
        short ov[8];
        #pragma unroll
        for (int j = 0; j < 8; j++){
            float v = acc[j];
            ov[j] = bf16s(v > 0.f ? v : expm1f(v));
        }
        *(bf16x8*)&emb[(size_t)n*64 + j8] = *(const bf16x8*)ov;
    }
}

// ---------------- scan phase 1: block-local ----------------
__global__ __launch_bounds__(256) void k_scan_local(const int* __restrict__ counts,
        int* __restrict__ rowptr, int* __restrict__ partials, int N){
    __shared__ int sd[256];
    int t = threadIdx.x;
    int i = blockIdx.x*256 + t;
    int v = (i < N) ? counts[i] : 0;
    sd[t] = v;
    __syncthreads();
    #pragma unroll
    for (int off = 1; off < 256; off <<= 1){
        int a = (t >= off) ? sd[t - off] : 0;
        __syncthreads();
        sd[t] += a;
        __syncthreads();
    }
    if (i < N) rowptr[i] = sd[t] - v;
    if (t == 255) partials[blockIdx.x] = sd[255];
}

// ---------------- scan phase 2: apply offsets; emit self-loop at bucket head ----------------
__global__ __launch_bounds__(256) void k_scan_fin(const int* __restrict__ partials,
        int* __restrict__ rowptr, int* __restrict__ cursor, int* __restrict__ srcs,
        int N, int NB){
    __shared__ int sd[256];
    int b = blockIdx.x, t = threadIdx.x;
    int off = 0, total = 0;
    for (int base = 0; base < NB; base += 256){
        int v = (base + t < NB) ? partials[base + t] : 0;
        __syncthreads();
        sd[t] = v;
        __syncthreads();
        #pragma unroll
        for (int o2 = 1; o2 < 256; o2 <<= 1){
            int a = (t >= o2) ? sd[t - o2] : 0;
            __syncthreads();
            sd[t] += a;
            __syncthreads();
        }
        if (b >= base && b < base + 256){
            int idx = b - base;
            int local = (idx == 0) ? 0 : sd[idx - 1];
            off = total + local;
        }
        total += sd[255];
    }
    int i = b*256 + t;
    if (i < N){
        int r = rowptr[i] + off;
        rowptr[i] = r;
        srcs[r]   = i;        // self-loop at bucket head (ordered writes, no amplification)
        cursor[i] = r + 1;    // real edges scatter after it
    }
    if (b == NB-1 && t == 255) rowptr[N] = total;
}

// ---------------- merged: GEMM1 (blocks < nG) | scatter of real edges (blocks >= nG) ----------------
__global__ __launch_bounds__(256, 3) void k_sg(
        const int* __restrict__ ei, int* __restrict__ cursor, int* __restrict__ srcs,
        const void* __restrict__ highv, const bf16* __restrict__ emb,
        const bf16* __restrict__ Bp, const void* __restrict__ attS,
        const void* __restrict__ attD, bf16* __restrict__ h1,
        float* __restrict__ a_s, float* __restrict__ a_d,
        const int* __restrict__ flag, int N, int E, int nG){
    const int RS = 260;
    __shared__ float eb[16*260 + 16];
    __shared__ float att[512];
    int t = threadIdx.x;
    if ((int)blockIdx.x >= nG){
        // ---- scatter role (real edges only; self-loops placed by scan_fin) ----
        int i = (blockIdx.x - nG)*256 + t;
        if (i < E){
            int src = ei[i];
            int dst = ei[E + i];
            int pos = atomicAdd(&cursor[dst], 1);
            srcs[pos] = src;
        }
        return;
    }
    // ---- GEMM1 role ----
    int isb = *flag;
    att[t] = cvtf(attS, t, isb);
    att[256 + t] = cvtf(attD, t, isb);
    int w = t >> 6, lane = t & 63;
    int m_lo = lane & 15, quad = lane >> 4;
    int m0 = blockIdx.x * 64;
    int mr[4];
    #pragma unroll
    for (int rt = 0; rt < 4; rt++){
        int m = m0 + rt*16 + m_lo;
        mr[rt] = m < N ? m : N-1;
    }
    f32x4 acc[4][4];
    #pragma unroll
    for (int rt = 0; rt < 4; rt++)
        #pragma unroll
        for (int ct = 0; ct < 4; ct++) acc[rt][ct] = (f32x4){0.f,0.f,0.f,0.f};

    #pragma unroll 2
    for (int kt = 0; kt < 6; kt++){
        bf16x8 a[4], b[4];
        if (kt < 4){
            #pragma unroll
            for (int rt = 0; rt < 4; rt++)
                a[rt] = load8(highv, (size_t)mr[rt]*128 + kt*32 + quad*8, isb);
        } else {
            #pragma unroll
            for (int rt = 0; rt < 4; rt++)
                a[rt] = *(const bf16x8*)&emb[(size_t)mr[rt]*64 + (kt-4)*32 + quad*8];
        }
        #pragma unroll
        for (int ct = 0; ct < 4; ct++)
            b[ct] = *(const bf16x8*)&Bp[(size_t)(((w*4 + ct)*6 + kt)*64 + lane)*8];
        #pragma unroll
        for (int rt = 0; rt < 4; rt++)
            #pragma unroll
            for (int ct = 0; ct < 4; ct++)
                acc[rt][ct] = __builtin_amdgcn_mfma_f32_16x16x32_bf16(a[rt], b[ct], acc[rt][ct], 0, 0, 0);
    }

    #pragma unroll 1
    for (int rt = 0; rt < 4; rt++){
        __syncthreads();
        #pragma unroll
        for (int ct = 0; ct < 4; ct++)
            #pragma unroll
            for (int reg = 0; reg < 4; reg++)
                eb[(quad*4 + reg)*RS + w*64 + ct*16 + m_lo] = acc[rt][ct][reg];
        __syncthreads();
        int r = t >> 4, cb = t & 15;
        int c0 = cb * 16;
        int m = m0 + rt*16 + r;
        f32x4 v[4];
        #pragma unroll
        for (int p = 0; p < 4; p++) v[p] = *(const f32x4*)&eb[r*RS + c0 + p*4];
        float ps = 0.f, pd = 0.f;
        #pragma unroll
        for (int p = 0; p < 4; p++)
            #pragma unroll
            for (int j = 0; j < 4; j++){
                ps += v[p][j] * att[c0 + p*4 + j];
                pd += v[p][j] * att[256 + c0 + p*4 + j];
            }
        if (m < N){
            short ov[16];
            #pragma unroll
            for (int p = 0; p < 4; p++)
                #pragma unroll
                for (int j = 0; j < 4; j++) ov[p*4+j] = bf16s(v[p][j]);
            *(bf16x8*)&h1[(size_t)m*256 + c0]     = *(const bf16x8*)&ov[0];
            *(bf16x8*)&h1[(size_t)m*256 + c0 + 8] = *(const bf16x8*)&ov[8];
        }
        ps += __shfl_xor(ps, 1);
        pd += __shfl_xor(pd, 1);
        if (((t & 1) == 0) && m < N){
            int hd = cb >> 1;
            a_s[m*8 + hd] = ps;
            a_d[m*8 + hd] = pd;
        }
    }
}

// ---------------- layer-1: single-sweep unnormalized softmax aggregate + elu + bias ----------------
__global__ __launch_bounds__(256) void k_edge1(const int* __restrict__ rowptr,
        const int* __restrict__ srcs, const float* __restrict__ a_s,
        const float* __restrict__ a_d, const bf16* __restrict__ h1,
        const void* __restrict__ b1, bf16* __restrict__ x2,
        const int* __restrict__ flag, int N){
    int t = threadIdx.x;
    int lane = t & 63, wv = t >> 6;
    int n = blockIdx.x*4 + wv;
    if (n >= N) return;
    int beg = rowptr[n];
    int deg = rowptr[n+1] - beg;

    int cl = lane & 31;          // channel group: channels cl*8..cl*8+7
    int hb = cl >> 2;            // head of this group
    int half = lane >> 5;        // edge parity
    float adb = a_d[n*8 + hb];

    float acc[8];
    #pragma unroll
    for (int j = 0; j < 8; j++) acc[j] = 0.f;
    float z = 0.f;

    int e = half;
    for (; e + 6 < deg; e += 8){
        int s0 = srcs[beg + e];
        int s1 = srcs[beg + e + 2];
        int s2 = srcs[beg + e + 4];
        int s3 = srcs[beg + e + 6];
        float w0 = __expf(fminf(lrelu(a_s[s0*8 + hb] + adb), 80.f));
        float w1 = __expf(fminf(lrelu(a_s[s1*8 + hb] + adb), 80.f));
        float w2 = __expf(fminf(lrelu(a_s[s2*8 + hb] + adb), 80.f));
        float w3 = __expf(fminf(lrelu(a_s[s3*8 + hb] + adb), 80.f));
        bf16x8 v0 = *(const bf16x8*)&h1[(size_t)s0*256 + cl*8];
        bf16x8 v1 = *(const bf16x8*)&h1[(size_t)s1*256 + cl*8];
        bf16x8 v2 = *(const bf16x8*)&h1[(size_t)s2*256 + cl*8];
        bf16x8 v3 = *(const bf16x8*)&h1[(size_t)s3*256 + cl*8];
        z += (w0 + w1) + (w2 + w3);
        #pragma unroll
        for (int j = 0; j < 8; j++) acc[j] += w0 * bfbits(v0[j]);
        #pragma unroll
        for (int j = 0; j < 8; j++) acc[j] += w1 * bfbits(v1[j]);
        #pragma unroll
        for (int j = 0; j < 8; j++) acc[j] += w2 * bfbits(v2[j]);
        #pragma unroll
        for (int j = 0; j < 8; j++) acc[j] += w3 * bfbits(v3[j]);
    }
    for (; e < deg; e += 2){
        int s = srcs[beg + e];
        float w = __expf(fminf(lrelu(a_s[s*8 + hb] + adb), 80.f));
        bf16x8 hv = *(const bf16x8*)&h1[(size_t)s*256 + cl*8];
        z += w;
        #pragma unroll
        for (int j = 0; j < 8; j++) acc[j] += w * bfbits(hv[j]);
    }
    #pragma unroll
    for (int j = 0; j < 8; j++) acc[j] += __shfl_xor(acc[j], 32);
    z += __shfl_xor(z, 32);
    float rz = 1.f / (z + 1e-16f);

    if (half == 0){
        int isb = *flag;
        bf16x8 bv = load8(b1, cl*8, isb);
        short ov[8];
        #pragma unroll
        for (int j = 0; j < 8; j++){
            float v = acc[j] * rz + bfbits(bv[j]);
            ov[j] = bf16s(v > 0.f ? v : expm1f(v));
        }
        *(bf16x8*)&x2[(size_t)n*256 + cl*8] = *(const bf16x8*)ov;
    }
}

// ---------------- GEMM2 (MFMA) + attention scalars layer 2 ----------------
__global__ __launch_bounds__(256) void k_gemm2(const bf16* __restrict__ x2,
        const bf16* __restrict__ Bp2, const void* __restrict__ attS,
        const void* __restrict__ attD, float* __restrict__ h2,
        float* __restrict__ a2s, float* __restrict__ a2d,
        const int* __restrict__ flag, int N){
    int t = threadIdx.x;
    int isb = *flag;
    int w = t >> 6, lane = t & 63;
    int m_lo = lane & 15, quad = lane >> 4;
    int m0 = blockIdx.x*64 + w*16;
    int mr = m0 + m_lo; if (mr >= N) mr = N-1;
    f32x4 acc = (f32x4){0.f,0.f,0.f,0.f};
    #pragma unroll
    for (int kt = 0; kt < 8; kt++){
        bf16x8 a = *(const bf16x8*)&x2[(size_t)mr*256 + kt*32 + quad*8];
        bf16x8 b = *(const bf16x8*)&Bp2[(size_t)(kt*64 + lane)*8];
        acc = __builtin_amdgcn_mfma_f32_16x16x32_bf16(a, b, acc, 0, 0, 0);
    }
    float s2 = (m_lo < 8) ? cvtf(attS, m_lo, isb) : 0.f;
    float d2 = (m_lo < 8) ? cvtf(attD, m_lo, isb) : 0.f;
    #pragma unroll
    for (int reg = 0; reg < 4; reg++){
        int m = m0 + quad*4 + reg;
        float val = acc[reg];
        float ps = val * s2, pd = val * d2;
        ps += __shfl_xor(ps, 1); ps += __shfl_xor(ps, 2);
        ps += __shfl_xor(ps, 4); ps += __shfl_xor(ps, 8);
        pd += __shfl_xor(pd, 1); pd += __shfl_xor(pd, 2);
        pd += __shfl_xor(pd, 4); pd += __shfl_xor(pd, 8);
        if (m < N){
            if (m_lo < 8) h2[(size_t)m*8 + m_lo] = val;
            if (m_lo == 0){ a2s[m] = ps; a2d[m] = pd; }
        }
    }
}

// ---------------- layer-2: single-sweep aggregate + bias + log_softmax ----------------
__global__ __launch_bounds__(256) void k_edge2(const int* __restrict__ rowptr,
        const int* __restrict__ srcs, const float* __restrict__ a2s,
        const float* __restrict__ a2d, const float* __restrict__ h2,
        const void* __restrict__ b2, void* __restrict__ outv,
        const int* __restrict__ flag, int N){
    int t = threadIdx.x;
    int lane = t & 63, wv = t >> 6;
    int n = blockIdx.x*4 + wv;
    if (n >= N) return;
    int beg = rowptr[n];
    int deg = rowptr[n+1] - beg;
    float adh = a2d[n];
    int ep = lane >> 3, c = lane & 7;
    float acc = 0.f, z = 0.f;
    for (int e = ep; e < deg; e += 8){
        int s = srcs[beg + e];
        float w = __expf(fminf(lrelu(a2s[s] + adh), 80.f));
        z += w;
        acc += w * h2[(size_t)s*8 + c];
    }
    acc += __shfl_xor(acc, 8);
    acc += __shfl_xor(acc, 16);
    acc += __shfl_xor(acc, 32);
    z += __shfl_xor(z, 8);
    z += __shfl_xor(z, 16);
    z += __shfl_xor(z, 32);
    int isb = *flag;
    float val = acc / (z + 1e-16f) + cvtf(b2, c, isb);
    float mx = val;
    mx = fmaxf(mx, __shfl_xor(mx, 1));
    mx = fmaxf(mx, __shfl_xor(mx, 2));
    mx = fmaxf(mx, __shfl_xor(mx, 4));
    float se = __expf(val - mx);
    se += __shfl_xor(se, 1); se += __shfl_xor(se, 2); se += __shfl_xor(se, 4);
    float r = val - mx - __logf(se);
    if (lane < 8){
        if (isb) ((bf16*)outv)[(size_t)n*8 + c] = f2bf(r);
        else     ((float*)outv)[(size_t)n*8 + c] = r;
    }
}

extern "C" void kernel_launch(void* const* d_in, const int* in_sizes, int n_in,
                              void* d_out, int out_size, void* d_ws, size_t ws_size,
                              hipStream_t stream) {
    const int* ei = (const int*)d_in[2];
    const int N = in_sizes[0] / 128;
    const int E = in_sizes[2] / 2;
    const int ET = E + N;
    const int NB = (N + 255) / 256;

    char* p = (char*)d_ws;
    auto alloc = [&](size_t bytes) -> void* {
        char* r = p;
        p += (bytes + 255) & ~(size_t)255;
        return (void*)r;
    };
    int*   flag     = (int*)  alloc(256);
    int*   counts   = (int*)  alloc((size_t)N*4);
    int*   rowptr   = (int*)  alloc((size_t)(N+1)*4);
    int*   cursor   = (int*)  alloc((size_t)N*4);
    int*   srcs     = (int*)  alloc((size_t)ET*4);
    int*   partials = (int*)  alloc((size_t)NB*4);
    bf16*  Bp       = (bf16*) alloc((size_t)192*256*2);
    bf16*  Bp2      = (bf16*) alloc((size_t)8*64*8*2);
    bf16*  emb      = (bf16*) alloc((size_t)N*64*2);
    bf16*  h1       = (bf16*) alloc((size_t)N*256*2);
    float* a_s      = (float*)alloc((size_t)N*8*4);
    float* a_d      = (float*)alloc((size_t)N*8*4);
    bf16*  x2       = (bf16*) alloc((size_t)N*256*2);
    float* h2       = (float*)alloc((size_t)N*8*4);
    float* a2s      = (float*)alloc((size_t)N*4);
    float* a2d      = (float*)alloc((size_t)N*4);

    k_init<<<NB, 256, 0, stream>>>((const unsigned short*)d_in[0], flag, counts, N);

    {
        int nEmb  = (N + 31)/32;
        int nPack = (16*6*64*8 + 8*64*8 + 255)/256;
        int nCnt  = 1024;
        k_prep<<<nEmb + nPack + nCnt, 256, 0, stream>>>(d_in[1], d_in[3], d_in[4],
                d_in[5], d_in[9], emb, Bp, Bp2, ei, counts, flag, N, E, nEmb, nPack, nCnt);
    }
    k_scan_local<<<NB, 256, 0, stream>>>(counts, rowptr, partials, N);
    k_scan_fin  <<<NB, 256, 0, stream>>>(partials, rowptr, cursor, srcs, N, NB);
    {
        int nG = (N + 63)/64;
        int nScat = (E + 255)/256;
        k_sg<<<nG + nScat, 256, 0, stream>>>(ei, cursor, srcs,
                d_in[0], emb, Bp, d_in[6], d_in[7], h1, a_s, a_d, flag, N, E, nG);
    }
    k_edge1<<<(N + 3)/4, 256, 0, stream>>>(rowptr, srcs, a_s, a_d, h1, d_in[8], x2, flag, N);
    k_gemm2<<<(N + 63)/64, 256, 0, stream>>>(x2, Bp2, d_in[10], d_in[11], h2, a2s, a2d, flag, N);
    k_edge2<<<(N + 3)/4, 256, 0, stream>>>(rowptr, srcs, a2s, a2d, h2, d_in[12], d_out, flag, N);
}